// Round 4
// baseline (6893.735 us; speedup 1.0000x reference)
//
#include <hip/hip_runtime.h>
#include <hip/hip_fp16.h>

// LSTMDecoder: B=32768, LATENT=32, HID=128, NVAR=9, T=60, 2 layers.
// R4: [bias|se] const-folded into register C-init (gc), G1 bias via b1vec C-init,
// bfold merged into gc after t=0. Per-step: G0=16kt, G1=16kt. Issue-early
// register-array weight loads (fully unrolled). Non-temporal output flush.
// X cols: 0..127 h0[0] | 128..255 h0[1] | 256..383 h1
// (init reuse: 0..15 bias, 16..143 se, 144..175 z)

#define TSTEP 60
#define ROWS  64
#define CS    392
#define KTSZ  8192
#define NKT0  25
#define NKT1  17
#define NKTI  11
#define NKTO  9
#define NP0   (NKT0*KTSZ)
#define NP1   (NKT1*KTSZ)
#define NPI   (NKTI*KTSZ)
#define NPO   (NKTO*512)
#define TAIL  (NP0+NP1+NPI+NPO)

typedef _Float16 f16x8  __attribute__((ext_vector_type(8)));
typedef float    f32x16 __attribute__((ext_vector_type(16)));
typedef float    f32x4  __attribute__((ext_vector_type(4)));

__device__ __forceinline__ float sigm(float x) {
    float e = __builtin_amdgcn_exp2f(x * -1.4426950408889634f);
    return __builtin_amdgcn_rcpf(1.0f + e);
}
__device__ __forceinline__ float tanh_(float x) {
    float e = __builtin_amdgcn_exp2f(x * -2.8853900817779268f);
    return __builtin_amdgcn_rcpf(1.0f + e) * 2.0f - 1.0f;
}

// ---------------- prep: permute + f16-convert + fold, kt-major [kt][512][16] ----
// Wp0 (u'=h*4+g, r=g*128+h): k0=b_ih0+b_hh0 ; k1=bfold(unused col) ; k16..143=W_ih0[r,9:137] ;
//      k144..271=W_hh0[r,:] ; k272..399=W_ih0[r,:9]@W_out
// Wp1: k0..127=W_ih1 ; k128..255=W_hh1 ; k256=bias(unused)
// Wpi (u'=h*4+q, r=q*128+h): k0=b_init ; k16..143=W_init[r,32:160] ; k144..175=W_init[r,0:32]
// Wop (32 rows): v<9: k0..127=W_out[v,:]
// tail f32: b1f[512]=b_ih1+b_hh1 (permuted), bff[512]=W_ih0[:, :9]@b_out (permuted)
__global__ void prep_kernel(const float* __restrict__ Winit, const float* __restrict__ binit,
                            const float* __restrict__ Wih0, const float* __restrict__ Whh0,
                            const float* __restrict__ bih0, const float* __restrict__ bhh0,
                            const float* __restrict__ Wih1, const float* __restrict__ Whh1,
                            const float* __restrict__ bih1, const float* __restrict__ bhh1,
                            const float* __restrict__ Wout, const float* __restrict__ bout,
                            _Float16* __restrict__ ws)
{
    int i = blockIdx.x * 256 + threadIdx.x;
    _Float16* Wp0 = ws;
    _Float16* Wp1 = ws + NP0;
    _Float16* Wpi = ws + NP0 + NP1;
    _Float16* Wop = ws + NP0 + NP1 + NPI;

    if (i < NP0) {
        int kt = i >> 13, rem = i & 8191, u = rem >> 4, e = rem & 15;
        int k = kt * 16 + e;
        int g = u & 3, h = u >> 2, r = g * 128 + h;
        float v = 0.0f;
        if (k == 0)                   v = bih0[r] + bhh0[r];
        else if (k >= 16 && k < 144)  v = Wih0[r * 137 + 9 + (k - 16)];
        else if (k >= 144 && k < 272) v = Whh0[r * 128 + (k - 144)];
        else if (k >= 272)            { for (int q = 0; q < 9; q++) v += Wih0[r * 137 + q] * Wout[q * 128 + (k - 272)]; }
        Wp0[i] = (_Float16)v;
    }
    if (i < NP1) {
        int kt = i >> 13, rem = i & 8191, u = rem >> 4, e = rem & 15;
        int k = kt * 16 + e;
        int g = u & 3, h = u >> 2, r = g * 128 + h;
        float v = 0.0f;
        if (k < 128)      v = Wih1[r * 128 + k];
        else if (k < 256) v = Whh1[r * 128 + (k - 128)];
        Wp1[i] = (_Float16)v;
    }
    if (i < NPI) {
        int kt = i >> 13, rem = i & 8191, u = rem >> 4, e = rem & 15;
        int k = kt * 16 + e;
        int q = u & 3, h = u >> 2, r = q * 128 + h;
        float v = 0.0f;
        if (k == 0)                   v = binit[r];
        else if (k >= 16 && k < 144)  v = Winit[r * 160 + 32 + (k - 16)];
        else if (k >= 144 && k < 176) v = Winit[r * 160 + (k - 144)];
        Wpi[i] = (_Float16)v;
    }
    if (i < NPO) {
        int kt = i >> 9, rem = i & 511, vv = rem >> 4, e = rem & 15;
        int k = kt * 16 + e;
        float v = 0.0f;
        if (vv < 9 && k < 128) v = Wout[vv * 128 + k];
        Wop[i] = (_Float16)v;
    }
    if (i < 512) {
        int g = i & 3, h = i >> 2, r = g * 128 + h;
        float* b1f = (float*)(ws + TAIL);
        float* bff = b1f + 512;
        b1f[i] = bih1[r] + bhh1[r];
        float s = 0.0f;
        for (int q = 0; q < 9; q++) s += Wih0[r * 137 + q] * bout[q];
        bff[i] = s;
    }
}

// ---------------- main persistent kernel ----------------
__global__ __launch_bounds__(512, 4) void lstm_main(
    const float* __restrict__ z, const int* __restrict__ scen,
    const float* __restrict__ emb, const _Float16* __restrict__ ws,
    const float* __restrict__ bout, float* __restrict__ out)
{
    __shared__ _Float16 Xs[ROWS * CS];
    __shared__ _Float16 Os[ROWS * 63];

    const int tid = threadIdx.x;
    const int w   = tid >> 6;
    const int l   = tid & 63;
    const int hi  = l >> 5;
    const int ln  = l & 31;
    const int hi8 = hi * 8;
    const int Bb  = blockIdx.x * ROWS;

    const _Float16* Wp0 = ws;
    const _Float16* Wp1 = ws + NP0;
    const _Float16* Wpi = ws + NP0 + NP1;
    const _Float16* Wop = ws + NP0 + NP1 + NPI;
    const float*    b1f = (const float*)(ws + TAIL);
    const float*    bff = b1f + 512;

    const int xk  = ((ln >> 1) & 7) << 3;
    const int xb0 = ln * CS;
    const int xb1 = (32 + ln) * CS;
    const int rwa = (w * 64 + ln) * 16 + hi8;

    // ---- zero + fill init LDS ----
    for (int i = tid; i < ROWS * CS; i += 512) Xs[i] = (_Float16)0.0f;
    __syncthreads();
    for (int i = tid; i < ROWS * 128; i += 512) {
        int b = i >> 7, j = i & 127;
        int sc  = scen[Bb + b];
        int key = ((b >> 1) & 7) << 3;
        Xs[b * CS + ((16 + j) ^ key)] = (_Float16)emb[sc * 128 + j];
    }
    for (int i = tid; i < ROWS * 32; i += 512) {
        int b = i >> 5, j = i & 31;
        int key = ((b >> 1) & 7) << 3;
        Xs[b * CS + ((144 + j) ^ key)] = (_Float16)z[(Bb + b) * 32 + j];
    }
    if (tid < ROWS) {
        int key = ((tid >> 1) & 7) << 3;
        Xs[tid * CS + (0 ^ key)] = (_Float16)1.0f;
    }
    __syncthreads();

    // ---- per-lane constant registers ----
    f32x16 b1v[2];
#pragma unroll
    for (int rt = 0; rt < 2; rt++)
#pragma unroll
    for (int rg = 0; rg < 4; rg++) {
        f32x4 v = *(const f32x4*)(b1f + 64 * w + 32 * rt + 8 * rg + 4 * hi);
#pragma unroll
        for (int j = 0; j < 4; j++) b1v[rt][4 * rg + j] = v[j];
    }
    float bo0 = 0, bo1 = 0, bo2 = 0, bo3 = 0, bo4 = 0;
    if (w < 2) {
        if (hi == 0) { bo0 = bout[0]; bo1 = bout[1]; bo2 = bout[2]; bo3 = bout[3]; bo4 = bout[8]; }
        else         { bo0 = bout[4]; bo1 = bout[5]; bo2 = bout[6]; bo3 = bout[7]; }
    }

    float c0r[2][4][2], c1r[2][4][2];
    f32x16 gc[2][2] = {};

    // ---- gc GEMM: Wp0 kt0..8 over [bias|se] ----
    {
#pragma unroll 1
        for (int kt = 0; kt < 9; kt++) {
            f16x8 a0 = *(const f16x8*)(Wp0 + rwa + kt * KTSZ);
            f16x8 a1 = *(const f16x8*)(Wp0 + rwa + kt * KTSZ + 512);
            int xc = kt * 16 + hi8;
            f16x8 b0 = *(const f16x8*)(Xs + xb0 + (xc ^ xk));
            f16x8 b1 = *(const f16x8*)(Xs + xb1 + (xc ^ xk));
            gc[0][0] = __builtin_amdgcn_mfma_f32_32x32x16_f16(a0, b0, gc[0][0], 0, 0, 0);
            gc[0][1] = __builtin_amdgcn_mfma_f32_32x32x16_f16(a0, b1, gc[0][1], 0, 0, 0);
            gc[1][0] = __builtin_amdgcn_mfma_f32_32x32x16_f16(a1, b0, gc[1][0], 0, 0, 0);
            gc[1][1] = __builtin_amdgcn_mfma_f32_32x32x16_f16(a1, b1, gc[1][1], 0, 0, 0);
        }
    }
    // ---- h_init GEMM: Wpi kt0..10 over [bias|se|z] ----
    {
        f32x16 acc[2][2] = {};
#pragma unroll 1
        for (int kt = 0; kt < NKTI; kt++) {
            f16x8 a0 = *(const f16x8*)(Wpi + rwa + kt * KTSZ);
            f16x8 a1 = *(const f16x8*)(Wpi + rwa + kt * KTSZ + 512);
            int xc = kt * 16 + hi8;
            f16x8 b0 = *(const f16x8*)(Xs + xb0 + (xc ^ xk));
            f16x8 b1 = *(const f16x8*)(Xs + xb1 + (xc ^ xk));
            acc[0][0] = __builtin_amdgcn_mfma_f32_32x32x16_f16(a0, b0, acc[0][0], 0, 0, 0);
            acc[0][1] = __builtin_amdgcn_mfma_f32_32x32x16_f16(a0, b1, acc[0][1], 0, 0, 0);
            acc[1][0] = __builtin_amdgcn_mfma_f32_32x32x16_f16(a1, b0, acc[1][0], 0, 0, 0);
            acc[1][1] = __builtin_amdgcn_mfma_f32_32x32x16_f16(a1, b1, acc[1][1], 0, 0, 0);
        }
        __syncthreads();   // all init reads done before overwrite
#pragma unroll
        for (int rt = 0; rt < 2; rt++)
#pragma unroll
        for (int ct = 0; ct < 2; ct++) {
            int xb = ct ? xb1 : xb0;
#pragma unroll
            for (int rg = 0; rg < 4; rg++) {
                int hid = (w << 4) + rt * 8 + 2 * rg + hi;
                c0r[rt][rg][ct] = acc[rt][ct][4 * rg + 1];
                c1r[rt][rg][ct] = acc[rt][ct][4 * rg + 3];
                Xs[xb + ((0 + hid) ^ xk)]   = (_Float16)acc[rt][ct][4 * rg + 0];
                Xs[xb + ((256 + hid) ^ xk)] = (_Float16)acc[rt][ct][4 * rg + 2];
            }
        }
    }
    __syncthreads();

    // ---- time loop ----
#pragma unroll 1
    for (int t = 0; t < TSTEP; t++) {
        const int p = t & 1;
        const int hb  = p << 7;          // h0 read buffer
        const int hbn = (p ^ 1) << 7;    // h0 write buffer

        // ===== G0: issue-early loads, then MFMA (C-init = gc) =====
        f32x16 acc[2][2];
        {
            f16x8 A0[16], A1[16];
#pragma unroll
            for (int i = 0; i < 16; i++) {
                A0[i] = *(const f16x8*)(Wp0 + rwa + (9 + i) * KTSZ);
                A1[i] = *(const f16x8*)(Wp0 + rwa + (9 + i) * KTSZ + 512);
            }
            {
                int xc = hb + hi8;
                f16x8 b0 = *(const f16x8*)(Xs + xb0 + (xc ^ xk));
                f16x8 b1 = *(const f16x8*)(Xs + xb1 + (xc ^ xk));
                acc[0][0] = __builtin_amdgcn_mfma_f32_32x32x16_f16(A0[0], b0, gc[0][0], 0, 0, 0);
                acc[0][1] = __builtin_amdgcn_mfma_f32_32x32x16_f16(A0[0], b1, gc[0][1], 0, 0, 0);
                acc[1][0] = __builtin_amdgcn_mfma_f32_32x32x16_f16(A1[0], b0, gc[1][0], 0, 0, 0);
                acc[1][1] = __builtin_amdgcn_mfma_f32_32x32x16_f16(A1[0], b1, gc[1][1], 0, 0, 0);
            }
#pragma unroll
            for (int i = 1; i < 8; i++) {
                int xc = hb + i * 16 + hi8;
                f16x8 b0 = *(const f16x8*)(Xs + xb0 + (xc ^ xk));
                f16x8 b1 = *(const f16x8*)(Xs + xb1 + (xc ^ xk));
                acc[0][0] = __builtin_amdgcn_mfma_f32_32x32x16_f16(A0[i], b0, acc[0][0], 0, 0, 0);
                acc[0][1] = __builtin_amdgcn_mfma_f32_32x32x16_f16(A0[i], b1, acc[0][1], 0, 0, 0);
                acc[1][0] = __builtin_amdgcn_mfma_f32_32x32x16_f16(A1[i], b0, acc[1][0], 0, 0, 0);
                acc[1][1] = __builtin_amdgcn_mfma_f32_32x32x16_f16(A1[i], b1, acc[1][1], 0, 0, 0);
            }
            if (t > 0) {
#pragma unroll
                for (int i = 8; i < 16; i++) {
                    int xc = 256 + (i - 8) * 16 + hi8;
                    f16x8 b0 = *(const f16x8*)(Xs + xb0 + (xc ^ xk));
                    f16x8 b1 = *(const f16x8*)(Xs + xb1 + (xc ^ xk));
                    acc[0][0] = __builtin_amdgcn_mfma_f32_32x32x16_f16(A0[i], b0, acc[0][0], 0, 0, 0);
                    acc[0][1] = __builtin_amdgcn_mfma_f32_32x32x16_f16(A0[i], b1, acc[0][1], 0, 0, 0);
                    acc[1][0] = __builtin_amdgcn_mfma_f32_32x32x16_f16(A1[i], b0, acc[1][0], 0, 0, 0);
                    acc[1][1] = __builtin_amdgcn_mfma_f32_32x32x16_f16(A1[i], b1, acc[1][1], 0, 0, 0);
                }
            }
        }

        // ===== E0: write h0n into buffer hbn (not read this phase) =====
#pragma unroll
        for (int rt = 0; rt < 2; rt++)
#pragma unroll
        for (int ct = 0; ct < 2; ct++) {
            int xb = ct ? xb1 : xb0;
#pragma unroll
            for (int rg = 0; rg < 4; rg++) {
                float gi = acc[rt][ct][4 * rg + 0];
                float gf = acc[rt][ct][4 * rg + 1];
                float gg = acc[rt][ct][4 * rg + 2];
                float go = acc[rt][ct][4 * rg + 3];
                float c = sigm(gf) * c0r[rt][rg][ct] + sigm(gi) * tanh_(gg);
                c0r[rt][rg][ct] = c;
                float h = sigm(go) * tanh_(c);
                int hid = (w << 4) + rt * 8 + 2 * rg + hi;
                Xs[xb + ((hbn + hid) ^ xk)] = (_Float16)h;
            }
        }
        if (t == 0) {   // merge bfold into gc (register-only)
#pragma unroll
            for (int rt = 0; rt < 2; rt++)
#pragma unroll
            for (int rg = 0; rg < 4; rg++) {
                f32x4 v = *(const f32x4*)(bff + 64 * w + 32 * rt + 8 * rg + 4 * hi);
#pragma unroll
                for (int j = 0; j < 4; j++) {
                    gc[rt][0][4 * rg + j] += v[j];
                    gc[rt][1][4 * rg + j] += v[j];
                }
            }
        }
        __syncthreads();   // barrier A: h0n visible

        // ===== G1: issue-early loads, MFMA (C-init = b1v) =====
        {
            f16x8 A0[16], A1[16];
#pragma unroll
            for (int i = 0; i < 16; i++) {
                A0[i] = *(const f16x8*)(Wp1 + rwa + i * KTSZ);
                A1[i] = *(const f16x8*)(Wp1 + rwa + i * KTSZ + 512);
            }
            {
                int xc = hbn + hi8;
                f16x8 b0 = *(const f16x8*)(Xs + xb0 + (xc ^ xk));
                f16x8 b1 = *(const f16x8*)(Xs + xb1 + (xc ^ xk));
                acc[0][0] = __builtin_amdgcn_mfma_f32_32x32x16_f16(A0[0], b0, b1v[0], 0, 0, 0);
                acc[0][1] = __builtin_amdgcn_mfma_f32_32x32x16_f16(A0[0], b1, b1v[0], 0, 0, 0);
                acc[1][0] = __builtin_amdgcn_mfma_f32_32x32x16_f16(A1[0], b0, b1v[1], 0, 0, 0);
                acc[1][1] = __builtin_amdgcn_mfma_f32_32x32x16_f16(A1[0], b1, b1v[1], 0, 0, 0);
            }
#pragma unroll
            for (int i = 1; i < 16; i++) {
                int xc = (i < 8 ? hbn + i * 16 : 256 + (i - 8) * 16) + hi8;
                f16x8 b0 = *(const f16x8*)(Xs + xb0 + (xc ^ xk));
                f16x8 b1 = *(const f16x8*)(Xs + xb1 + (xc ^ xk));
                acc[0][0] = __builtin_amdgcn_mfma_f32_32x32x16_f16(A0[i], b0, acc[0][0], 0, 0, 0);
                acc[0][1] = __builtin_amdgcn_mfma_f32_32x32x16_f16(A0[i], b1, acc[0][1], 0, 0, 0);
                acc[1][0] = __builtin_amdgcn_mfma_f32_32x32x16_f16(A1[i], b0, acc[1][0], 0, 0, 0);
                acc[1][1] = __builtin_amdgcn_mfma_f32_32x32x16_f16(A1[i], b1, acc[1][1], 0, 0, 0);
            }
        }
        __syncthreads();   // barrier B: G1 reads done before h1 overwrite

        // ===== E1: write h1n in place (cols 256..383) =====
#pragma unroll
        for (int rt = 0; rt < 2; rt++)
#pragma unroll
        for (int ct = 0; ct < 2; ct++) {
            int xb = ct ? xb1 : xb0;
#pragma unroll
            for (int rg = 0; rg < 4; rg++) {
                float gi = acc[rt][ct][4 * rg + 0];
                float gf = acc[rt][ct][4 * rg + 1];
                float gg = acc[rt][ct][4 * rg + 2];
                float go = acc[rt][ct][4 * rg + 3];
                float c = sigm(gf) * c1r[rt][rg][ct] + sigm(gi) * tanh_(gg);
                c1r[rt][rg][ct] = c;
                float h = sigm(go) * tanh_(c);
                int hid = (w << 4) + rt * 8 + 2 * rg + hi;
                Xs[xb + ((256 + hid) ^ xk)] = (_Float16)h;
            }
        }
        __syncthreads();   // barrier C: h1n visible

        // ===== out-proj (waves 0,1) -> Os staging =====
        const int tc = t % 7;
        if (w < 2) {
            const int xb = w ? xb1 : xb0;
            f32x16 aC = {};
#pragma unroll
            for (int kt = 0; kt < 8; kt++) {
                f16x8 av = *(const f16x8*)(Wop + kt * 512 + ln * 16 + hi8);
                int xc = 256 + kt * 16 + hi8;
                f16x8 bv = *(const f16x8*)(Xs + xb + (xc ^ xk));
                aC = __builtin_amdgcn_mfma_f32_32x32x16_f16(av, bv, aC, 0, 0, 0);
            }
            _Float16* os = Os + (w * 32 + ln) * 63 + tc * 9;
            if (hi == 0) {
                os[0] = (_Float16)(aC[0] + bo0); os[1] = (_Float16)(aC[1] + bo1);
                os[2] = (_Float16)(aC[2] + bo2); os[3] = (_Float16)(aC[3] + bo3);
                os[8] = (_Float16)(aC[4] + bo4);
            } else {
                os[4] = (_Float16)(aC[0] + bo0); os[5] = (_Float16)(aC[1] + bo1);
                os[6] = (_Float16)(aC[2] + bo2); os[7] = (_Float16)(aC[3] + bo3);
            }
        }

        // ===== chunked non-temporal flush =====
        if (tc == 6 || t == TSTEP - 1) {
            __syncthreads();
            const int t0 = t - tc;
            const int run = (tc + 1) * 9;
            const int tot = ROWS * run;
            for (int q = tid; q < tot; q += 512) {
                int row = q / run, j = q - row * run;
                __builtin_nontemporal_store((float)Os[row * 63 + j],
                    out + (size_t)(Bb + row) * (TSTEP * 9) + t0 * 9 + j);
            }
        }
    }
}

extern "C" void kernel_launch(void* const* d_in, const int* in_sizes, int n_in,
                              void* d_out, int out_size, void* d_ws, size_t ws_size,
                              hipStream_t stream) {
    const float* z     = (const float*)d_in[0];
    const int*   scen  = (const int*)d_in[1];
    const float* emb   = (const float*)d_in[3];
    const float* Winit = (const float*)d_in[4];
    const float* binit = (const float*)d_in[5];
    const float* Wih0  = (const float*)d_in[6];
    const float* Whh0  = (const float*)d_in[7];
    const float* bih0  = (const float*)d_in[8];
    const float* bhh0  = (const float*)d_in[9];
    const float* Wih1  = (const float*)d_in[10];
    const float* Whh1  = (const float*)d_in[11];
    const float* bih1  = (const float*)d_in[12];
    const float* bhh1  = (const float*)d_in[13];
    const float* Wout  = (const float*)d_in[14];
    const float* bout  = (const float*)d_in[15];
    _Float16* ws  = (_Float16*)d_ws;
    float*    out = (float*)d_out;

    prep_kernel<<<(NP0 + 255) / 256, 256, 0, stream>>>(
        Winit, binit, Wih0, Whh0, bih0, bhh0, Wih1, Whh1, bih1, bhh1, Wout, bout, ws);
    lstm_main<<<512, 512, 0, stream>>>(z, scen, emb, ws, bout, out);
}

// Round 6
// 2020.959 us; speedup vs baseline: 3.4111x; 3.4111x over previous
//
#include <hip/hip_runtime.h>
#include <hip/hip_fp16.h>

// LSTMDecoder: B=32768, LATENT=32, HID=128, NVAR=9, T=60, 2 layers.
// R6 (= R5 fixed): ROWS=128/block (1 block/CU, 256 blocks). Un-folded W_out
// (out-proj on chain, 3 barriers/step). se+bias via Gse[128][4][4] scenario
// table C-init. G0 = 9 kt (prev + h0), G1 = 16 kt (h0n + h1). kt-major
// coalesced weights. Full-unrolled kt loops; launch_bounds(512,2).
// X cols: 0..15 prev | 16..143 h0a | 144..271 h0b | 272..399 h1a | 400..527 h1b
// (init reuse: se at 144..271, z at 272..303, bias-1.0 at col 304)

#define TSTEP 60
#define ROWS  128
#define CS    536          // 1072 B/row: 16B-aligned, dword stride 268
#define KTSZ  8192
#define OW0   0
#define OW1   73728        // after Wp0: 9 kt
#define OWI   204800       // after Wp1: 16 kt
#define OWO   294912       // after Wpi: 11 kt
#define OEND  299008       // after Wop: 8*512
// f32 tail at ws+OEND: gsew[2048], b1w[512]

typedef _Float16 f16x8  __attribute__((ext_vector_type(8)));
typedef float    f32x16 __attribute__((ext_vector_type(16)));
typedef float    f32x4  __attribute__((ext_vector_type(4)));

__device__ __forceinline__ float sigm(float x) {
    float e = __builtin_amdgcn_exp2f(x * -1.4426950408889634f);
    return __builtin_amdgcn_rcpf(1.0f + e);
}
__device__ __forceinline__ float tanh_(float x) {
    float e = __builtin_amdgcn_exp2f(x * -2.8853900817779268f);
    return __builtin_amdgcn_rcpf(1.0f + e) * 2.0f - 1.0f;
}

// ---------------- prep: permute + f16 + kt-major [kt][512][16] ----------------
// u' = h*4+g (r = g*128+h) so each lane's C/D quad = (i,f,g,o) of one hid unit.
// Wp0: kt0 = W_ih0[r, 0:9] (prev, padded to 16); kt1..8 = W_hh0
// Wp1: kt0..7 = W_ih1 (vs h0n); kt8..15 = W_hh1 (vs h1)
// Wpi (u'=h*4+q, q:h0,c0,h1,c1): kt0..7 = W_init se-part; kt8,9 = z-part; kt10 e0 = b_init
// Wop: [8][32][16], rows 0..8 = W_out
// b1w[h*4+g] = (b_ih1+b_hh1)[r];  gsew via gse_kernel (needs emb)
__global__ void prep_kernel(const float* __restrict__ Winit, const float* __restrict__ binit,
                            const float* __restrict__ Wih0, const float* __restrict__ Whh0,
                            const float* __restrict__ bih0, const float* __restrict__ bhh0,
                            const float* __restrict__ Wih1, const float* __restrict__ Whh1,
                            const float* __restrict__ bih1, const float* __restrict__ bhh1,
                            const float* __restrict__ Wout, const float* __restrict__ bout,
                            _Float16* __restrict__ ws)
{
    int i = blockIdx.x * 256 + threadIdx.x;
    float* gsw = (float*)(ws + OEND);
    float* b1w = gsw + 2048;

    if (i < 73728) {   // Wp0
        int kt = i >> 13, rem = i & 8191, u = rem >> 4, e = rem & 15;
        int g = u & 3, h = u >> 2, r = g * 128 + h;
        float v = 0.0f;
        if (kt == 0) { if (e < 9) v = Wih0[r * 137 + e]; }
        else         v = Whh0[r * 128 + (kt - 1) * 16 + e];
        ws[OW0 + i] = (_Float16)v;
    }
    if (i < 131072) {  // Wp1
        int kt = i >> 13, rem = i & 8191, u = rem >> 4, e = rem & 15;
        int g = u & 3, h = u >> 2, r = g * 128 + h;
        float v = (kt < 8) ? Wih1[r * 128 + kt * 16 + e]
                           : Whh1[r * 128 + (kt - 8) * 16 + e];
        ws[OW1 + i] = (_Float16)v;
    }
    if (i < 90112) {   // Wpi
        int kt = i >> 13, rem = i & 8191, u = rem >> 4, e = rem & 15;
        int q = u & 3, h = u >> 2, r = q * 128 + h;
        float v = 0.0f;
        if (kt < 8)       v = Winit[r * 160 + 32 + kt * 16 + e];
        else if (kt < 10) v = Winit[r * 160 + (kt - 8) * 16 + e];
        else if (e == 0)  v = binit[r];
        ws[OWI + i] = (_Float16)v;
    }
    if (i < 4096) {    // Wop
        int kt = i >> 9, rem = i & 511, vv = rem >> 4, e = rem & 15;
        float v = (vv < 9) ? Wout[vv * 128 + kt * 16 + e] : 0.0f;
        ws[OWO + i] = (_Float16)v;
    }
    if (i < 512) {     // b1w
        int h = i >> 2, g = i & 3, r = g * 128 + h;
        b1w[i] = bih1[r] + bhh1[r];
    }
}

// gsew[h][s][g] = (b_ih0+b_hh0)[r] + W_ih0[r,9:137] @ emb[s]
__global__ void gse_kernel(const float* __restrict__ Wih0, const float* __restrict__ bih0,
                           const float* __restrict__ bhh0, const float* __restrict__ emb,
                           _Float16* __restrict__ ws)
{
    int i = blockIdx.x * 256 + threadIdx.x;   // 2048 total
    if (i >= 2048) return;
    float* gsw = (float*)(ws + OEND);
    int h = i >> 4, s = (i >> 2) & 3, g = i & 3, r = g * 128 + h;
    float v = bih0[r] + bhh0[r];
    for (int k = 0; k < 128; k++) v += Wih0[r * 137 + 9 + k] * emb[s * 128 + k];
    gsw[i] = v;
}

// ---------------- main persistent kernel ----------------
__global__ __launch_bounds__(512, 2) void lstm_main(
    const float* __restrict__ z, const int* __restrict__ scen,
    const float* __restrict__ emb, const _Float16* __restrict__ ws,
    const float* __restrict__ bout, float* __restrict__ out)
{
    __shared__ _Float16 Xs[ROWS * CS];     // 137216 B
    __shared__ _Float16 Os[ROWS * 63];     // 16128 B
    __shared__ float    Gse[2048];         // 8192 B
    __shared__ float    B1t[512];          // 2048 B

    const int tid = threadIdx.x;
    const int w   = tid >> 6;
    const int l   = tid & 63;
    const int hi  = l >> 5;
    const int ln  = l & 31;
    const int hi8 = hi * 8;
    const int Bb  = blockIdx.x * ROWS;

    const _Float16* Wp0 = ws + OW0;
    const _Float16* Wp1 = ws + OW1;
    const _Float16* Wpi = ws + OWI;
    const _Float16* Wop = ws + OWO;
    const float*    gsw = (const float*)(ws + OEND);
    const float*    b1w = gsw + 2048;

    int xb[4], sc[4];
#pragma unroll
    for (int ct = 0; ct < 4; ct++) {
        int b = ct * 32 + ln;
        xb[ct] = b * CS;
        sc[ct] = scen[Bb + b];
    }
    const int rwa = (w * 64 + ln) * 16 + hi8;

    // ---- zero + fill LDS ----
    for (int i = tid; i < ROWS * CS; i += 512) Xs[i] = (_Float16)0.0f;
    for (int i = tid; i < 2048; i += 512) Gse[i] = gsw[i];
    if (tid < 512) B1t[tid] = b1w[tid];
    __syncthreads();
    for (int i = tid; i < ROWS * 128; i += 512) {
        int b = i >> 7, j = i & 127;
        Xs[b * CS + 144 + j] = (_Float16)emb[scen[Bb + b] * 128 + j];
    }
    for (int i = tid; i < ROWS * 32; i += 512) {
        int b = i >> 5, j = i & 31;
        Xs[b * CS + 272 + j] = (_Float16)z[(Bb + b) * 32 + j];
    }
    if (tid < ROWS) Xs[tid * CS + 304] = (_Float16)1.0f;
    __syncthreads();

    float c0r[2][4][4], c1r[2][4][4];   // [rt][rg][ct]

    // ---- init GEMM: 11 kt over [se|z|1] ----
    {
        f32x16 acc[2][4] = {};
#pragma unroll
        for (int kt = 0; kt < 11; kt++) {
            f16x8 a0 = *(const f16x8*)(Wpi + kt * KTSZ + rwa);
            f16x8 a1 = *(const f16x8*)(Wpi + kt * KTSZ + rwa + 512);
            int col = (kt < 8 ? 144 + kt * 16 : (kt < 10 ? 272 + (kt - 8) * 16 : 304)) + hi8;
#pragma unroll
            for (int ct = 0; ct < 4; ct++) {
                f16x8 bv = *(const f16x8*)(Xs + xb[ct] + col);
                acc[0][ct] = __builtin_amdgcn_mfma_f32_32x32x16_f16(a0, bv, acc[0][ct], 0, 0, 0);
                acc[1][ct] = __builtin_amdgcn_mfma_f32_32x32x16_f16(a1, bv, acc[1][ct], 0, 0, 0);
            }
        }
#pragma unroll
        for (int rt = 0; rt < 2; rt++)
#pragma unroll
        for (int ct = 0; ct < 4; ct++) {
#pragma unroll
            for (int rg = 0; rg < 4; rg++) {
                int hid = (w << 4) + rt * 8 + 2 * rg + hi;
                c0r[rt][rg][ct] = acc[rt][ct][4 * rg + 1];
                c1r[rt][rg][ct] = acc[rt][ct][4 * rg + 3];
                Xs[xb[ct] + 16 + hid]  = (_Float16)acc[rt][ct][4 * rg + 0];
                Xs[xb[ct] + 400 + hid] = (_Float16)acc[rt][ct][4 * rg + 2];
            }
        }
    }
    __syncthreads();

    float bo[5] = {0.f, 0.f, 0.f, 0.f, 0.f};
    if (w < 4) {
        if (hi == 0) { bo[0] = bout[0]; bo[1] = bout[1]; bo[2] = bout[2]; bo[3] = bout[3]; bo[4] = bout[8]; }
        else         { bo[0] = bout[4]; bo[1] = bout[5]; bo[2] = bout[6]; bo[3] = bout[7]; }
    }

    int hp = 16, hq = 144, vr = 400, vw = 272;

    // ---- time loop ----
#pragma unroll 1
    for (int t = 0; t < TSTEP; t++) {
        // ===== G0: C-init from Gse; kt0 = prev, kt1..8 = h0[hp] =====
        f32x16 acc[2][4];
#pragma unroll
        for (int rt = 0; rt < 2; rt++)
#pragma unroll
        for (int ct = 0; ct < 4; ct++) {
#pragma unroll
            for (int rg = 0; rg < 4; rg++) {
                f32x4 gv = *(const f32x4*)(Gse + ((w * 16 + rt * 8 + 2 * rg + hi) * 16 + sc[ct] * 4));
                acc[rt][ct][4 * rg + 0] = gv[0];
                acc[rt][ct][4 * rg + 1] = gv[1];
                acc[rt][ct][4 * rg + 2] = gv[2];
                acc[rt][ct][4 * rg + 3] = gv[3];
            }
        }
#pragma unroll
        for (int kt = 0; kt < 9; kt++) {
            f16x8 a0 = *(const f16x8*)(Wp0 + kt * KTSZ + rwa);
            f16x8 a1 = *(const f16x8*)(Wp0 + kt * KTSZ + rwa + 512);
            int col = (kt == 0 ? 0 : hp + (kt - 1) * 16) + hi8;
#pragma unroll
            for (int ct = 0; ct < 4; ct++) {
                f16x8 bv = *(const f16x8*)(Xs + xb[ct] + col);
                acc[0][ct] = __builtin_amdgcn_mfma_f32_32x32x16_f16(a0, bv, acc[0][ct], 0, 0, 0);
                acc[1][ct] = __builtin_amdgcn_mfma_f32_32x32x16_f16(a1, bv, acc[1][ct], 0, 0, 0);
            }
        }

        // ===== E0: write h0n -> h0[hq] (disjoint from reads) =====
#pragma unroll
        for (int rt = 0; rt < 2; rt++)
#pragma unroll
        for (int ct = 0; ct < 4; ct++) {
#pragma unroll
            for (int rg = 0; rg < 4; rg++) {
                float gi = acc[rt][ct][4 * rg + 0];
                float gf = acc[rt][ct][4 * rg + 1];
                float gg = acc[rt][ct][4 * rg + 2];
                float go = acc[rt][ct][4 * rg + 3];
                float c = sigm(gf) * c0r[rt][rg][ct] + sigm(gi) * tanh_(gg);
                c0r[rt][rg][ct] = c;
                float h = sigm(go) * tanh_(c);
                int hid = (w << 4) + rt * 8 + 2 * rg + hi;
                Xs[xb[ct] + hq + hid] = (_Float16)h;
            }
        }
        __syncthreads();   // barrier A: h0n visible

        // ===== G1: C-init from B1t; kt0..7 = h0n[hq], kt8..15 = h1[vr] =====
#pragma unroll
        for (int rt = 0; rt < 2; rt++) {
            f32x16 ci;
#pragma unroll
            for (int rg = 0; rg < 4; rg++) {
                f32x4 bv4 = *(const f32x4*)(B1t + (w * 16 + rt * 8 + 2 * rg + hi) * 4);
                ci[4 * rg + 0] = bv4[0]; ci[4 * rg + 1] = bv4[1];
                ci[4 * rg + 2] = bv4[2]; ci[4 * rg + 3] = bv4[3];
            }
#pragma unroll
            for (int ct = 0; ct < 4; ct++) acc[rt][ct] = ci;
        }
#pragma unroll
        for (int kt = 0; kt < 16; kt++) {
            f16x8 a0 = *(const f16x8*)(Wp1 + kt * KTSZ + rwa);
            f16x8 a1 = *(const f16x8*)(Wp1 + kt * KTSZ + rwa + 512);
            int col = (kt < 8 ? hq + kt * 16 : vr + (kt - 8) * 16) + hi8;
#pragma unroll
            for (int ct = 0; ct < 4; ct++) {
                f16x8 bv = *(const f16x8*)(Xs + xb[ct] + col);
                acc[0][ct] = __builtin_amdgcn_mfma_f32_32x32x16_f16(a0, bv, acc[0][ct], 0, 0, 0);
                acc[1][ct] = __builtin_amdgcn_mfma_f32_32x32x16_f16(a1, bv, acc[1][ct], 0, 0, 0);
            }
        }

        // ===== E1: write h1n -> h1[vw] (dbuf: G1 reads vr) =====
#pragma unroll
        for (int rt = 0; rt < 2; rt++)
#pragma unroll
        for (int ct = 0; ct < 4; ct++) {
#pragma unroll
            for (int rg = 0; rg < 4; rg++) {
                float gi = acc[rt][ct][4 * rg + 0];
                float gf = acc[rt][ct][4 * rg + 1];
                float gg = acc[rt][ct][4 * rg + 2];
                float go = acc[rt][ct][4 * rg + 3];
                float c = sigm(gf) * c1r[rt][rg][ct] + sigm(gi) * tanh_(gg);
                c1r[rt][rg][ct] = c;
                float h = sigm(go) * tanh_(c);
                int hid = (w << 4) + rt * 8 + 2 * rg + hi;
                Xs[xb[ct] + vw + hid] = (_Float16)h;
            }
        }
        __syncthreads();   // barrier B: h1n visible

        // ===== out-proj (waves 0..3, ct = w): prev + Os =====
        const int tc = t % 7;
        if (w < 4) {
            const int xo = (w * 32 + ln) * CS;
            f32x16 aC = {};
#pragma unroll
            for (int kt = 0; kt < 8; kt++) {
                f16x8 av = *(const f16x8*)(Wop + kt * 512 + ln * 16 + hi8);
                f16x8 bv = *(const f16x8*)(Xs + xo + vw + kt * 16 + hi8);
                aC = __builtin_amdgcn_mfma_f32_32x32x16_f16(av, bv, aC, 0, 0, 0);
            }
            _Float16* os = Os + (w * 32 + ln) * 63 + tc * 9;
            if (hi == 0) {
                float v0 = aC[0] + bo[0], v1 = aC[1] + bo[1], v2 = aC[2] + bo[2],
                      v3 = aC[3] + bo[3], v4 = aC[4] + bo[4];
                os[0] = (_Float16)v0; os[1] = (_Float16)v1; os[2] = (_Float16)v2;
                os[3] = (_Float16)v3; os[8] = (_Float16)v4;
                Xs[xo + 0] = (_Float16)v0; Xs[xo + 1] = (_Float16)v1;
                Xs[xo + 2] = (_Float16)v2; Xs[xo + 3] = (_Float16)v3;
                Xs[xo + 8] = (_Float16)v4;
            } else {
                float v0 = aC[0] + bo[0], v1 = aC[1] + bo[1], v2 = aC[2] + bo[2],
                      v3 = aC[3] + bo[3];
                os[4] = (_Float16)v0; os[5] = (_Float16)v1; os[6] = (_Float16)v2;
                os[7] = (_Float16)v3;
                Xs[xo + 4] = (_Float16)v0; Xs[xo + 5] = (_Float16)v1;
                Xs[xo + 6] = (_Float16)v2; Xs[xo + 7] = (_Float16)v3;
            }
        }
        __syncthreads();   // barrier C: prev + Os visible

        // ===== chunked non-temporal flush =====
        if (tc == 6 || t == TSTEP - 1) {
            const int t0 = t - tc;
            const int run = (tc + 1) * 9;
            const int tot = ROWS * run;
            for (int qq = tid; qq < tot; qq += 512) {
                int row = qq / run, j = qq - row * run;
                __builtin_nontemporal_store((float)Os[row * 63 + j],
                    out + (size_t)(Bb + row) * (TSTEP * 9) + t0 * 9 + j);
            }
        }
        int tmp = hp; hp = hq; hq = tmp;
        tmp = vr; vr = vw; vw = tmp;
    }
}

extern "C" void kernel_launch(void* const* d_in, const int* in_sizes, int n_in,
                              void* d_out, int out_size, void* d_ws, size_t ws_size,
                              hipStream_t stream) {
    const float* z     = (const float*)d_in[0];
    const int*   scen  = (const int*)d_in[1];
    const float* emb   = (const float*)d_in[3];
    const float* Winit = (const float*)d_in[4];
    const float* binit = (const float*)d_in[5];
    const float* Wih0  = (const float*)d_in[6];
    const float* Whh0  = (const float*)d_in[7];
    const float* bih0  = (const float*)d_in[8];
    const float* bhh0  = (const float*)d_in[9];
    const float* Wih1  = (const float*)d_in[10];
    const float* Whh1  = (const float*)d_in[11];
    const float* bih1  = (const float*)d_in[12];
    const float* bhh1  = (const float*)d_in[13];
    const float* Wout  = (const float*)d_in[14];
    const float* bout  = (const float*)d_in[15];
    _Float16* ws  = (_Float16*)d_ws;
    float*    out = (float*)d_out;

    prep_kernel<<<512, 256, 0, stream>>>(
        Winit, binit, Wih0, Whh0, bih0, bhh0, Wih1, Whh1, bih1, bhh1, Wout, bout, ws);
    gse_kernel<<<8, 256, 0, stream>>>(Wih0, bih0, bhh0, emb, ws);
    lstm_main<<<256, 512, 0, stream>>>(z, scen, emb, ws, bout, out);
}